// Round 11
// baseline (253.744 us; speedup 1.0000x reference)
//
#include <hip/hip_runtime.h>
#include <hip/hip_bf16.h>
#include <stdint.h>

// GCN encoder: h = relu(A(x@W1)+b1); hagg = A h; [mu|ls] = hagg@[Wmu|Wls] + [bmu|bls]
// A = sym-normalized adjacency with self-loops.
// - CSR build: deterministic chunked counting sort (zero global atomics in hot path;
//   round-5 lesson: same-address global atomics serialize at ~180ns each).
// - Degree-balanced scheduling (round-10 lesson: block retires at max of member
//   waves' degrees; Poisson-16 max-of-4 costs ~20%): nodes counting-sorted by
//   descending degree -> blocks get equal-degree nodes, heavy blocks first.
// - GEMMs: bf16 MFMA 16x16x32, W^T bf16 in LDS (row stride 136 kills conflicts).
// - Aggregation (round-8 form, at the L2-miss service floor ~2.6-2.9 TB/s):
//   one wave/node, half-wave edge pairing, 8-edge unroll. Fusion of agg2+GEMM2
//   REVERTED (round-10: straggler cost > 51MB round-trip saving).

static inline size_t align_up(size_t x, size_t a) { return (x + a - 1) / a * a; }

typedef __attribute__((ext_vector_type(8))) short short8;
typedef __attribute__((ext_vector_type(4))) float f32x4;

#define BSHIFT 7
#define BNODES 128   // nodes per bucket
#define CHUNKS 512   // edge chunks
#define NBMAX 1024
#define NCHUNKN 256  // node chunks for degree sort
#define DBINS 256    // degree bins (clamped)

__device__ inline unsigned short f2bf(float f) {
    unsigned u = __float_as_uint(f);
    unsigned r = (u + 0x7FFFu + ((u >> 16) & 1u)) >> 16;  // RNE
    return (unsigned short)r;
}
__device__ inline float bf2f(unsigned v16) {
    return __uint_as_float(v16 << 16);
}

// Per-block edge-dtype detection (int64 high words all zero for ids < 2^31).
__device__ inline bool detect_i64_local(const void* ei, int lo, int hi, int t) {
    __shared__ int s_nz;
    if (t == 0) s_nz = 0;
    __syncthreads();
    int nz = 0;
    int lim = min(hi, lo + 1024);
    const int* p = (const int*)ei;
    for (int i = lo + t; i < lim; i += 256) {
        if (p[2 * i + 1] != 0) nz = 1;
    }
    if (nz) atomicOr(&s_nz, 1);
    __syncthreads();
    return s_nz == 0;
}

__device__ inline int load_idx2(const void* ei, bool is64, size_t pos, int n) {
    int v;
    if (is64) v = (int)((const long long*)ei)[pos];
    else      v = ((const int*)ei)[pos];
    return (v < 0) ? 0 : (v >= n ? n - 1 : v);
}

// ---------------- pass A: per-chunk bucket histogram (LDS atomics only) ----------------

__global__ __launch_bounds__(256) void chunk_hist_kernel(
        const void* __restrict__ ei, int* __restrict__ hmat,
        int E, int n, int nb, int epc) {
    __shared__ int hist[NBMAX];
    const int c = blockIdx.x, t = threadIdx.x;
    const int lo = min(E, c * epc), hi = min(E, lo + epc);
    bool is64 = detect_i64_local(ei, lo, hi, t);
    for (int i = t; i < nb; i += 256) hist[i] = 0;
    __syncthreads();
    for (int i = lo + t; i < hi; i += 256) {
        int d = load_idx2(ei, is64, (size_t)E + i, n);
        atomicAdd(&hist[d >> BSHIFT], 1);
    }
    __syncthreads();
    for (int i = t; i < nb; i += 256) hmat[(size_t)c * nb + i] = hist[i];
}

// ---------------- pass B1: per-bucket scan over chunks ----------------

__global__ __launch_bounds__(256) void bucket_scan_cols_kernel(
        int* __restrict__ hmat, int* __restrict__ btot, int nb) {
    __shared__ int tmp[256];
    const int b = blockIdx.x, t = threadIdx.x;
    const int c0 = 2 * t;
    int va = hmat[(size_t)c0 * nb + b];
    int vb = hmat[(size_t)(c0 + 1) * nb + b];
    int pair = va + vb;
    tmp[t] = pair;
    __syncthreads();
    for (int off = 1; off < 256; off <<= 1) {
        int u = (t >= off) ? tmp[t - off] : 0;
        __syncthreads();
        tmp[t] += u;
        __syncthreads();
    }
    int excl = tmp[t] - pair;
    hmat[(size_t)c0 * nb + b] = excl;
    hmat[(size_t)(c0 + 1) * nb + b] = excl + va;
    if (t == 255) btot[b] = tmp[255];
}

// ---------------- pass B2: scan totals -> bases (works for nb <= 1024) ----------------

__global__ void base_scan_kernel(const int* __restrict__ btot, int* __restrict__ bbase, int nb) {
    __shared__ int tmp[NBMAX];
    int t = threadIdx.x;
    int v = (t < nb) ? btot[t] : 0;
    tmp[t] = v;
    __syncthreads();
    for (int off = 1; off < NBMAX; off <<= 1) {
        int u = (t >= off) ? tmp[t - off] : 0;
        __syncthreads();
        tmp[t] += u;
        __syncthreads();
    }
    if (t < nb) bbase[t] = tmp[t] - v;  // exclusive
}

// ---------------- pass C: chunk scatter (LDS cursors, pre-reserved slots) ----------------

__global__ __launch_bounds__(256) void chunk_scatter_kernel(
        const void* __restrict__ ei, const int* __restrict__ hmat,
        const int* __restrict__ bbase, unsigned* __restrict__ binned,
        int E, int n, int nb, int epc) {
    __shared__ int lcur[NBMAX];
    const int c = blockIdx.x, t = threadIdx.x;
    const int lo = min(E, c * epc), hi = min(E, lo + epc);
    bool is64 = detect_i64_local(ei, lo, hi, t);
    for (int i = t; i < nb; i += 256) lcur[i] = hmat[(size_t)c * nb + i] + bbase[i];
    __syncthreads();
    for (int i = lo + t; i < hi; i += 256) {
        int s = load_idx2(ei, is64, i, n);
        int d = load_idx2(ei, is64, (size_t)E + i, n);
        int b = d >> BSHIFT;
        int pos = atomicAdd(&lcur[b], 1);  // LDS atomic: fast, block-local
        binned[pos] = ((unsigned)s << BSHIFT) | (unsigned)(d & (BNODES - 1));
    }
}

// ---------------- per-bucket CSR build (deg + dis + row ptrs + local scatter) ----------------

__global__ __launch_bounds__(256) void bucket_csr_kernel(
        const unsigned* __restrict__ binned, const int* __restrict__ bbase,
        const int* __restrict__ btot, float* __restrict__ dis,
        int* __restrict__ row_beg, int* __restrict__ row_end,
        int* __restrict__ csr_src, int n) {
    __shared__ int ldeg[BNODES];
    __shared__ int lscan[BNODES];
    __shared__ int lcur[BNODES];
    const int b = blockIdx.x;
    const int t = threadIdx.x;
    const int base = bbase[b];
    const int cnt = btot[b];

    if (t < BNODES) ldeg[t] = 0;
    __syncthreads();
    for (int i = t; i < cnt; i += 256) {
        unsigned w = binned[base + i];
        atomicAdd(&ldeg[w & (BNODES - 1)], 1);
    }
    __syncthreads();
    int v = (t < BNODES) ? ldeg[t] : 0;
    if (t < BNODES) lscan[t] = v;
    __syncthreads();
    for (int off = 1; off < BNODES; off <<= 1) {
        int u = (t < BNODES && t >= off) ? lscan[t - off] : 0;
        __syncthreads();
        if (t < BNODES) lscan[t] += u;
        __syncthreads();
    }
    if (t < BNODES) {
        int excl = lscan[t] - v;
        lcur[t] = excl;
        int node = (b << BSHIFT) + t;
        if (node < n) {
            dis[node] = rsqrtf((float)v + 1.0f);  // +1 self loop
            row_beg[node] = base + excl;
            row_end[node] = base + excl + v;
        }
    }
    __syncthreads();
    for (int i = t; i < cnt; i += 256) {
        unsigned w = binned[base + i];
        int pos = atomicAdd(&lcur[w & (BNODES - 1)], 1);
        csr_src[base + pos] = (int)(w >> BSHIFT);
    }
}

// ---------------- degree-balanced node permutation (descending degree) ----------------
// Same deterministic chunked counting-sort pattern, keyed on 255-min(deg,255).

__global__ __launch_bounds__(256) void node_deg_hist_kernel(
        const int* __restrict__ row_beg, const int* __restrict__ row_end,
        int* __restrict__ dh, int n, int npc) {
    __shared__ int hist[DBINS];
    const int c = blockIdx.x, t = threadIdx.x;
    hist[t] = 0;
    __syncthreads();
    const int lo = min(n, c * npc), hi = min(n, lo + npc);
    for (int i = lo + t; i < hi; i += 256) {
        int bin = (DBINS - 1) - min(row_end[i] - row_beg[i], DBINS - 1);
        atomicAdd(&hist[bin], 1);
    }
    __syncthreads();
    dh[c * DBINS + t] = hist[t];
}

__global__ __launch_bounds__(256) void deg_scan_cols_kernel(
        int* __restrict__ dh, int* __restrict__ dtot) {
    __shared__ int tmp[NCHUNKN];
    const int b = blockIdx.x, t = threadIdx.x;
    int v = dh[t * DBINS + b];
    tmp[t] = v;
    __syncthreads();
    for (int off = 1; off < NCHUNKN; off <<= 1) {
        int u = (t >= off) ? tmp[t - off] : 0;
        __syncthreads();
        tmp[t] += u;
        __syncthreads();
    }
    dh[t * DBINS + b] = tmp[t] - v;  // exclusive over chunks
    if (t == NCHUNKN - 1) dtot[b] = tmp[NCHUNKN - 1];
}

__global__ __launch_bounds__(256) void node_perm_scatter_kernel(
        const int* __restrict__ row_beg, const int* __restrict__ row_end,
        const int* __restrict__ dh, const int* __restrict__ dbase,
        int* __restrict__ perm, int n, int npc) {
    __shared__ int cur[DBINS];
    const int c = blockIdx.x, t = threadIdx.x;
    cur[t] = dh[c * DBINS + t] + dbase[t];
    __syncthreads();
    const int lo = min(n, c * npc), hi = min(n, lo + npc);
    for (int i = lo + t; i < hi; i += 256) {
        int bin = (DBINS - 1) - min(row_end[i] - row_beg[i], DBINS - 1);
        int pos = atomicAdd(&cur[bin], 1);  // LDS atomic
        perm[pos] = i;
    }
}

// ---------------- weight prep: transpose to [N][K] bf16 ----------------

__global__ void prep_weights_kernel(const float* __restrict__ W1,
                                    const float* __restrict__ Wmu,
                                    const float* __restrict__ Wls,
                                    unsigned short* __restrict__ Wt1,
                                    unsigned short* __restrict__ Wtcat) {
    int idx = blockIdx.x * 256 + threadIdx.x;
    if (idx < 16384) {
        int c = idx >> 7, k = idx & 127;
        Wt1[c * 128 + k] = f2bf(W1[k * 128 + c]);
    } else if (idx < 32768) {
        int i = idx - 16384;
        int j = i >> 7, k = i & 127;
        float v = (j < 64) ? Wmu[k * 64 + j] : Wls[k * 64 + (j - 64)];
        Wtcat[j * 128 + k] = f2bf(v);
    }
}

// ---------------- MFMA GEMM: [n x 128] @ [128 x 128] ----------------
// MODE 0: A fp32, out bf16 [n][128], no bias (gemm1; bias fused into agg1)
// MODE 1: A bf16, out fp32 split outA(cols 0..63)+outB(64..127), bias biasA/biasB

template <int MODE>
__global__ __launch_bounds__(256) void mfma_gemm_kernel(
        const void* __restrict__ Ax, const unsigned short* __restrict__ Wt,
        const float* __restrict__ biasA, const float* __restrict__ biasB,
        void* __restrict__ outA, void* __restrict__ outB, int n) {
    __shared__ unsigned short ws[128 * 136];  // row stride 136 elems (272B)
    const int tid = threadIdx.x;
    const int wave = tid >> 6, lane = tid & 63;
    const int brow = blockIdx.x * 64 + wave * 16;
    const int lr = lane & 15;   // A-row / B-col within 16-tile
    const int kg = lane >> 4;   // k-group 0..3
    const int k0 = kg * 8;

    for (int i = tid; i < 2048; i += 256) {
        int r = i >> 4, ci = i & 15;
        *(short8*)&ws[r * 136 + ci * 8] = *(const short8*)&Wt[r * 128 + ci * 8];
    }
    __syncthreads();

    int arow = brow + lr;
    if (arow >= n) arow = n - 1;  // clamp loads; stores guarded

    f32x4 acc[8];
#pragma unroll
    for (int t = 0; t < 8; ++t) acc[t] = (f32x4){0.f, 0.f, 0.f, 0.f};

#pragma unroll
    for (int c = 0; c < 4; ++c) {
        short8 a;
        if (MODE == 0) {
            const float* ap = (const float*)Ax + (size_t)arow * 128 + c * 32 + k0;
            float4 lo = *(const float4*)ap;
            float4 hi = *(const float4*)(ap + 4);
            a[0] = (short)f2bf(lo.x); a[1] = (short)f2bf(lo.y);
            a[2] = (short)f2bf(lo.z); a[3] = (short)f2bf(lo.w);
            a[4] = (short)f2bf(hi.x); a[5] = (short)f2bf(hi.y);
            a[6] = (short)f2bf(hi.z); a[7] = (short)f2bf(hi.w);
        } else {
            a = *(const short8*)((const unsigned short*)Ax + (size_t)arow * 128 + c * 32 + k0);
        }
#pragma unroll
        for (int t = 0; t < 8; ++t) {
            short8 bfr = *(const short8*)&ws[(t * 16 + lr) * 136 + c * 32 + k0];
            acc[t] = __builtin_amdgcn_mfma_f32_16x16x32_bf16(a, bfr, acc[t], 0, 0, 0);
        }
    }

    // C/D layout (m89): col = lane&15, row = (lane>>4)*4 + reg
    if (MODE == 0) {
        unsigned short* out = (unsigned short*)outA;
#pragma unroll
        for (int t = 0; t < 8; ++t) {
            int col = t * 16 + lr;
#pragma unroll
            for (int r = 0; r < 4; ++r) {
                int row = brow + kg * 4 + r;
                if (row < n) out[(size_t)row * 128 + col] = f2bf(acc[t][r]);
            }
        }
    } else {
        float* oA = (float*)outA;
        float* oB = (float*)outB;
#pragma unroll
        for (int t = 0; t < 8; ++t) {
            int col = t * 16 + lr;
            float bv = (col < 64) ? biasA[col] : biasB[col - 64];
#pragma unroll
            for (int r = 0; r < 4; ++r) {
                int row = brow + kg * 4 + r;
                if (row < n) {
                    float v = acc[t][r] + bv;
                    if (col < 64) oA[(size_t)row * 64 + col] = v;
                    else          oB[(size_t)row * 64 + (col - 64)] = v;
                }
            }
        }
    }
}

// ---------------- fused CSR aggregation: half-wave pairing, 8-edge unroll ----------------
// out[v] = act( dv*( sum_e dis[s_e]*x[s_e] + dv*x[v] ) + bias ),  dv = dis[v]
// Node order from degree-sorted perm (block waves get equal-degree nodes).

__global__ __launch_bounds__(256) void csr_agg_kernel(
        const unsigned short* __restrict__ hin, const int* __restrict__ row_beg,
        const int* __restrict__ row_end, const int* __restrict__ csr_src,
        const int* __restrict__ perm, const float* __restrict__ dis,
        const float* __restrict__ bias, unsigned short* __restrict__ out,
        int n, int relu) {
    int gid = blockIdx.x * 4 + (threadIdx.x >> 6);
    if (gid >= n) return;
    int node = perm[gid];
    const int lane = threadIdx.x & 63;
    const int hi_half = lane >> 5;            // 0: even edges, 1: odd edges
    const unsigned foff = (lane & 31) * 8;    // byte offset of this lane's 4 features
    int beg = row_beg[node], end = row_end[node];
    float dv = dis[node];

    const char* hinb = (const char*)hin;

    float a0x = 0.f, a0y = 0.f, a0z = 0.f, a0w = 0.f;
    float a1x = 0.f, a1y = 0.f, a1z = 0.f, a1w = 0.f;
    float a2x = 0.f, a2y = 0.f, a2z = 0.f, a2w = 0.f;
    float a3x = 0.f, a3y = 0.f, a3z = 0.f, a3w = 0.f;

    int e = beg;
    // main: 4 pairs = 8 edges per iteration
    for (; e + 7 < end; e += 8) {
        int s0 = csr_src[e + 0 + hi_half];
        int s1 = csr_src[e + 2 + hi_half];
        int s2 = csr_src[e + 4 + hi_half];
        int s3 = csr_src[e + 6 + hi_half];
        float w0 = dis[s0], w1 = dis[s1], w2 = dis[s2], w3 = dis[s3];
        uint2 d0 = *(const uint2*)(hinb + (size_t)s0 * 256 + foff);
        uint2 d1 = *(const uint2*)(hinb + (size_t)s1 * 256 + foff);
        uint2 d2 = *(const uint2*)(hinb + (size_t)s2 * 256 + foff);
        uint2 d3 = *(const uint2*)(hinb + (size_t)s3 * 256 + foff);
        a0x += bf2f(d0.x & 0xffffu) * w0; a0y += bf2f(d0.x >> 16) * w0;
        a0z += bf2f(d0.y & 0xffffu) * w0; a0w += bf2f(d0.y >> 16) * w0;
        a1x += bf2f(d1.x & 0xffffu) * w1; a1y += bf2f(d1.x >> 16) * w1;
        a1z += bf2f(d1.y & 0xffffu) * w1; a1w += bf2f(d1.y >> 16) * w1;
        a2x += bf2f(d2.x & 0xffffu) * w2; a2y += bf2f(d2.x >> 16) * w2;
        a2z += bf2f(d2.y & 0xffffu) * w2; a2w += bf2f(d2.y >> 16) * w2;
        a3x += bf2f(d3.x & 0xffffu) * w3; a3y += bf2f(d3.x >> 16) * w3;
        a3z += bf2f(d3.y & 0xffffu) * w3; a3w += bf2f(d3.y >> 16) * w3;
    }
    for (; e + 1 < end; e += 2) {
        int s = csr_src[e + hi_half];
        float w = dis[s];
        uint2 d = *(const uint2*)(hinb + (size_t)s * 256 + foff);
        a0x += bf2f(d.x & 0xffffu) * w; a0y += bf2f(d.x >> 16) * w;
        a0z += bf2f(d.y & 0xffffu) * w; a0w += bf2f(d.y >> 16) * w;
    }
    if (e < end) {  // odd tail at half weight in both halves
        int s = csr_src[e];
        float w = 0.5f * dis[s];
        uint2 d = *(const uint2*)(hinb + (size_t)s * 256 + foff);
        a1x += bf2f(d.x & 0xffffu) * w; a1y += bf2f(d.x >> 16) * w;
        a1z += bf2f(d.y & 0xffffu) * w; a1w += bf2f(d.y >> 16) * w;
    }

    float sx = (a0x + a1x) + (a2x + a3x);
    float sy = (a0y + a1y) + (a2y + a3y);
    float sz = (a0z + a1z) + (a2z + a3z);
    float sw = (a0w + a1w) + (a2w + a3w);
    sx += __shfl_xor(sx, 32, 64);
    sy += __shfl_xor(sy, 32, 64);
    sz += __shfl_xor(sz, 32, 64);
    sw += __shfl_xor(sw, 32, 64);

    uint2 sd = *(const uint2*)(hinb + (size_t)node * 256 + foff);
    sx = dv * (sx + dv * bf2f(sd.x & 0xffffu));
    sy = dv * (sy + dv * bf2f(sd.x >> 16));
    sz = dv * (sz + dv * bf2f(sd.y & 0xffffu));
    sw = dv * (sw + dv * bf2f(sd.y >> 16));

    if (bias) {
        float4 bb = *(const float4*)&bias[(lane & 31) * 4];
        sx += bb.x; sy += bb.y; sz += bb.z; sw += bb.w;
    }
    if (relu) {
        sx = fmaxf(sx, 0.f); sy = fmaxf(sy, 0.f);
        sz = fmaxf(sz, 0.f); sw = fmaxf(sw, 0.f);
    }
    if (lane < 32) {
        uint2 o;
        o.x = (unsigned)f2bf(sx) | ((unsigned)f2bf(sy) << 16);
        o.y = (unsigned)f2bf(sz) | ((unsigned)f2bf(sw) << 16);
        *(uint2*)((char*)out + (size_t)node * 256 + foff) = o;
    }
}

// ---------------- launcher ----------------

extern "C" void kernel_launch(void* const* d_in, const int* in_sizes, int n_in,
                              void* d_out, int out_size, void* d_ws, size_t ws_size,
                              hipStream_t stream) {
    const float* x   = (const float*)d_in[0];
    const void*  ei  = d_in[1];
    const float* W1  = (const float*)d_in[2];
    const float* b1  = (const float*)d_in[3];
    const float* Wmu = (const float*)d_in[4];
    const float* bmu = (const float*)d_in[5];
    const float* Wls = (const float*)d_in[6];
    const float* bls = (const float*)d_in[7];

    const int n = in_sizes[0] / 128;
    const int E = in_sizes[1] / 2;
    const int nb = (n + BNODES - 1) >> BSHIFT;      // 782 for n=100000 (<= NBMAX)
    const int epc = (E + CHUNKS - 1) / CHUNKS;      // edges per chunk
    const int npc = (n + NCHUNKN - 1) / NCHUNKN;    // nodes per chunk (deg sort)

    float* out   = (float*)d_out;
    float* outMu = out;
    float* outLs = out + (size_t)n * 64;

    char* w = (char*)d_ws;
    auto alloc = [&](size_t bytes) { char* p = w; w += align_up(bytes, 256); return p; };
    int*            hmat    = (int*)           alloc((size_t)CHUNKS * nb * 4);
    int*            btot    = (int*)           alloc(NBMAX * 4);
    int*            bbase   = (int*)           alloc(NBMAX * 4);
    unsigned*       binned  = (unsigned*)      alloc((size_t)E * 4);
    int*            row_beg = (int*)           alloc((size_t)n * 4);
    int*            row_end = (int*)           alloc((size_t)n * 4);
    float*          dis     = (float*)         alloc((size_t)n * 4);
    int*            csr_src = (int*)           alloc((size_t)E * 4);
    int*            dh      = (int*)           alloc((size_t)NCHUNKN * DBINS * 4);
    int*            dtot    = (int*)           alloc(DBINS * 4);
    int*            dbase   = (int*)           alloc(DBINS * 4);
    int*            perm    = (int*)           alloc((size_t)n * 4);
    unsigned short* Wt1     = (unsigned short*)alloc(128 * 128 * 2);
    unsigned short* Wtcat   = (unsigned short*)alloc(128 * 128 * 2);
    unsigned short* xW      = (unsigned short*)alloc((size_t)n * 128 * 2);
    unsigned short* h       = (unsigned short*)alloc((size_t)n * 128 * 2);
    unsigned short* hagg    = (unsigned short*)alloc((size_t)n * 128 * 2);

    // ---- graph preprocessing: deterministic chunked counting sort ----
    chunk_hist_kernel<<<CHUNKS, 256, 0, stream>>>(ei, hmat, E, n, nb, epc);
    bucket_scan_cols_kernel<<<nb, 256, 0, stream>>>(hmat, btot, nb);
    base_scan_kernel<<<1, NBMAX, 0, stream>>>(btot, bbase, nb);
    chunk_scatter_kernel<<<CHUNKS, 256, 0, stream>>>(ei, hmat, bbase, binned, E, n, nb, epc);
    bucket_csr_kernel<<<nb, 256, 0, stream>>>(binned, bbase, btot, dis, row_beg, row_end,
                                              csr_src, n);

    // ---- degree-balanced node permutation (descending degree) ----
    node_deg_hist_kernel<<<NCHUNKN, 256, 0, stream>>>(row_beg, row_end, dh, n, npc);
    deg_scan_cols_kernel<<<DBINS, NCHUNKN, 0, stream>>>(dh, dtot);
    base_scan_kernel<<<1, NBMAX, 0, stream>>>(dtot, dbase, DBINS);
    node_perm_scatter_kernel<<<NCHUNKN, 256, 0, stream>>>(row_beg, row_end, dh, dbase,
                                                          perm, n, npc);

    prep_weights_kernel<<<128, 256, 0, stream>>>(W1, Wmu, Wls, Wt1, Wtcat);

    const int gblocks = (n + 63) / 64;

    // ---- layer 1: h = relu(A(x@W1) + b1) ----
    mfma_gemm_kernel<0><<<gblocks, 256, 0, stream>>>(x, Wt1, nullptr, nullptr, xW, nullptr, n);
    csr_agg_kernel<<<(n + 3) / 4, 256, 0, stream>>>(xW, row_beg, row_end, csr_src, perm,
                                                    dis, b1, h, n, 1);

    // ---- layer 2+3: hagg = A h; [mu|ls] = hagg @ [Wmu|Wls] + [bmu|bls] ----
    csr_agg_kernel<<<(n + 3) / 4, 256, 0, stream>>>(h, row_beg, row_end, csr_src, perm,
                                                    dis, nullptr, hagg, n, 0);
    mfma_gemm_kernel<1><<<gblocks, 256, 0, stream>>>(hagg, Wtcat, bmu, bls, outMu, outLs, n);
}

// Round 12
// 236.724 us; speedup vs baseline: 1.0719x; 1.0719x over previous
//
#include <hip/hip_runtime.h>
#include <hip/hip_bf16.h>
#include <stdint.h>

// GCN encoder: h = relu(A(x@W1)+b1); hagg = A h; [mu|ls] = hagg@[Wmu|Wls] + [bmu|bls]
// A = sym-normalized adjacency with self-loops.
// FINAL CONFIGURATION (best measured, round-8 equivalent):
// - CSR build: deterministic chunked counting sort, zero global atomics in hot
//   path (round-5: same-address global atomics serialize ~180ns each); per-block
//   edge-dtype detection (round-9, saves a launch).
// - GEMMs: bf16 MFMA 16x16x32, W^T bf16 in LDS (row stride 136 kills conflicts).
// - Aggregation: one wave/node, half-wave edge pairing, 8-edge unroll. At the
//   L2-miss service floor ~2.6-2.9 TB/s on a pinned ~196MB/pass fetch
//   (8 XCDs x 25.6MB table, uniform random gather). Attacks that failed:
//   deeper unroll (r9, -4%), agg+GEMM fusion (r10, -30% via 16-wave straggler),
//   degree-balanced perm (r11, -3% via indirection traffic).

static inline size_t align_up(size_t x, size_t a) { return (x + a - 1) / a * a; }

typedef __attribute__((ext_vector_type(8))) short short8;
typedef __attribute__((ext_vector_type(4))) float f32x4;

#define BSHIFT 7
#define BNODES 128   // nodes per bucket
#define CHUNKS 512   // edge chunks
#define NBMAX 1024

__device__ inline unsigned short f2bf(float f) {
    unsigned u = __float_as_uint(f);
    unsigned r = (u + 0x7FFFu + ((u >> 16) & 1u)) >> 16;  // RNE
    return (unsigned short)r;
}
__device__ inline float bf2f(unsigned v16) {
    return __uint_as_float(v16 << 16);
}

// Per-block edge-dtype detection (int64 high words all zero for ids < 2^31).
__device__ inline bool detect_i64_local(const void* ei, int lo, int hi, int t) {
    __shared__ int s_nz;
    if (t == 0) s_nz = 0;
    __syncthreads();
    int nz = 0;
    int lim = min(hi, lo + 1024);
    const int* p = (const int*)ei;
    for (int i = lo + t; i < lim; i += 256) {
        if (p[2 * i + 1] != 0) nz = 1;
    }
    if (nz) atomicOr(&s_nz, 1);
    __syncthreads();
    return s_nz == 0;
}

__device__ inline int load_idx2(const void* ei, bool is64, size_t pos, int n) {
    int v;
    if (is64) v = (int)((const long long*)ei)[pos];
    else      v = ((const int*)ei)[pos];
    return (v < 0) ? 0 : (v >= n ? n - 1 : v);
}

// ---------------- pass A: per-chunk bucket histogram (LDS atomics only) ----------------

__global__ __launch_bounds__(256) void chunk_hist_kernel(
        const void* __restrict__ ei, int* __restrict__ hmat,
        int E, int n, int nb, int epc) {
    __shared__ int hist[NBMAX];
    const int c = blockIdx.x, t = threadIdx.x;
    const int lo = min(E, c * epc), hi = min(E, lo + epc);
    bool is64 = detect_i64_local(ei, lo, hi, t);
    for (int i = t; i < nb; i += 256) hist[i] = 0;
    __syncthreads();
    for (int i = lo + t; i < hi; i += 256) {
        int d = load_idx2(ei, is64, (size_t)E + i, n);
        atomicAdd(&hist[d >> BSHIFT], 1);
    }
    __syncthreads();
    for (int i = t; i < nb; i += 256) hmat[(size_t)c * nb + i] = hist[i];
}

// ---------------- pass B1: per-bucket scan over chunks ----------------

__global__ __launch_bounds__(256) void bucket_scan_cols_kernel(
        int* __restrict__ hmat, int* __restrict__ btot, int nb) {
    __shared__ int tmp[256];
    const int b = blockIdx.x, t = threadIdx.x;
    const int c0 = 2 * t;
    int va = hmat[(size_t)c0 * nb + b];
    int vb = hmat[(size_t)(c0 + 1) * nb + b];
    int pair = va + vb;
    tmp[t] = pair;
    __syncthreads();
    for (int off = 1; off < 256; off <<= 1) {
        int u = (t >= off) ? tmp[t - off] : 0;
        __syncthreads();
        tmp[t] += u;
        __syncthreads();
    }
    int excl = tmp[t] - pair;
    hmat[(size_t)c0 * nb + b] = excl;
    hmat[(size_t)(c0 + 1) * nb + b] = excl + va;
    if (t == 255) btot[b] = tmp[255];
}

// ---------------- pass B2: scan bucket totals -> bases ----------------

__global__ void base_scan_kernel(const int* __restrict__ btot, int* __restrict__ bbase, int nb) {
    __shared__ int tmp[NBMAX];
    int t = threadIdx.x;
    int v = (t < nb) ? btot[t] : 0;
    tmp[t] = v;
    __syncthreads();
    for (int off = 1; off < NBMAX; off <<= 1) {
        int u = (t >= off) ? tmp[t - off] : 0;
        __syncthreads();
        tmp[t] += u;
        __syncthreads();
    }
    if (t < nb) bbase[t] = tmp[t] - v;  // exclusive
}

// ---------------- pass C: chunk scatter (LDS cursors, pre-reserved slots) ----------------

__global__ __launch_bounds__(256) void chunk_scatter_kernel(
        const void* __restrict__ ei, const int* __restrict__ hmat,
        const int* __restrict__ bbase, unsigned* __restrict__ binned,
        int E, int n, int nb, int epc) {
    __shared__ int lcur[NBMAX];
    const int c = blockIdx.x, t = threadIdx.x;
    const int lo = min(E, c * epc), hi = min(E, lo + epc);
    bool is64 = detect_i64_local(ei, lo, hi, t);
    for (int i = t; i < nb; i += 256) lcur[i] = hmat[(size_t)c * nb + i] + bbase[i];
    __syncthreads();
    for (int i = lo + t; i < hi; i += 256) {
        int s = load_idx2(ei, is64, i, n);
        int d = load_idx2(ei, is64, (size_t)E + i, n);
        int b = d >> BSHIFT;
        int pos = atomicAdd(&lcur[b], 1);  // LDS atomic: fast, block-local
        binned[pos] = ((unsigned)s << BSHIFT) | (unsigned)(d & (BNODES - 1));
    }
}

// ---------------- per-bucket CSR build (deg + dis + row ptrs + local scatter) ----------------

__global__ __launch_bounds__(256) void bucket_csr_kernel(
        const unsigned* __restrict__ binned, const int* __restrict__ bbase,
        const int* __restrict__ btot, float* __restrict__ dis,
        int* __restrict__ row_beg, int* __restrict__ row_end,
        int* __restrict__ csr_src, int n) {
    __shared__ int ldeg[BNODES];
    __shared__ int lscan[BNODES];
    __shared__ int lcur[BNODES];
    const int b = blockIdx.x;
    const int t = threadIdx.x;
    const int base = bbase[b];
    const int cnt = btot[b];

    if (t < BNODES) ldeg[t] = 0;
    __syncthreads();
    for (int i = t; i < cnt; i += 256) {
        unsigned w = binned[base + i];
        atomicAdd(&ldeg[w & (BNODES - 1)], 1);
    }
    __syncthreads();
    int v = (t < BNODES) ? ldeg[t] : 0;
    if (t < BNODES) lscan[t] = v;
    __syncthreads();
    for (int off = 1; off < BNODES; off <<= 1) {
        int u = (t < BNODES && t >= off) ? lscan[t - off] : 0;
        __syncthreads();
        if (t < BNODES) lscan[t] += u;
        __syncthreads();
    }
    if (t < BNODES) {
        int excl = lscan[t] - v;
        lcur[t] = excl;
        int node = (b << BSHIFT) + t;
        if (node < n) {
            dis[node] = rsqrtf((float)v + 1.0f);  // +1 self loop
            row_beg[node] = base + excl;
            row_end[node] = base + excl + v;
        }
    }
    __syncthreads();
    for (int i = t; i < cnt; i += 256) {
        unsigned w = binned[base + i];
        int pos = atomicAdd(&lcur[w & (BNODES - 1)], 1);
        csr_src[base + pos] = (int)(w >> BSHIFT);
    }
}

// ---------------- weight prep: transpose to [N][K] bf16 ----------------

__global__ void prep_weights_kernel(const float* __restrict__ W1,
                                    const float* __restrict__ Wmu,
                                    const float* __restrict__ Wls,
                                    unsigned short* __restrict__ Wt1,
                                    unsigned short* __restrict__ Wtcat) {
    int idx = blockIdx.x * 256 + threadIdx.x;
    if (idx < 16384) {
        int c = idx >> 7, k = idx & 127;
        Wt1[c * 128 + k] = f2bf(W1[k * 128 + c]);
    } else if (idx < 32768) {
        int i = idx - 16384;
        int j = i >> 7, k = i & 127;
        float v = (j < 64) ? Wmu[k * 64 + j] : Wls[k * 64 + (j - 64)];
        Wtcat[j * 128 + k] = f2bf(v);
    }
}

// ---------------- MFMA GEMM: [n x 128] @ [128 x 128] ----------------
// MODE 0: A fp32, out bf16 [n][128], no bias (gemm1; bias fused into agg1)
// MODE 1: A bf16, out fp32 split outA(cols 0..63)+outB(64..127), bias biasA/biasB

template <int MODE>
__global__ __launch_bounds__(256) void mfma_gemm_kernel(
        const void* __restrict__ Ax, const unsigned short* __restrict__ Wt,
        const float* __restrict__ biasA, const float* __restrict__ biasB,
        void* __restrict__ outA, void* __restrict__ outB, int n) {
    __shared__ unsigned short ws[128 * 136];  // row stride 136 elems (272B)
    const int tid = threadIdx.x;
    const int wave = tid >> 6, lane = tid & 63;
    const int brow = blockIdx.x * 64 + wave * 16;
    const int lr = lane & 15;   // A-row / B-col within 16-tile
    const int kg = lane >> 4;   // k-group 0..3
    const int k0 = kg * 8;

    for (int i = tid; i < 2048; i += 256) {
        int r = i >> 4, ci = i & 15;
        *(short8*)&ws[r * 136 + ci * 8] = *(const short8*)&Wt[r * 128 + ci * 8];
    }
    __syncthreads();

    int arow = brow + lr;
    if (arow >= n) arow = n - 1;  // clamp loads; stores guarded

    f32x4 acc[8];
#pragma unroll
    for (int t = 0; t < 8; ++t) acc[t] = (f32x4){0.f, 0.f, 0.f, 0.f};

#pragma unroll
    for (int c = 0; c < 4; ++c) {
        short8 a;
        if (MODE == 0) {
            const float* ap = (const float*)Ax + (size_t)arow * 128 + c * 32 + k0;
            float4 lo = *(const float4*)ap;
            float4 hi = *(const float4*)(ap + 4);
            a[0] = (short)f2bf(lo.x); a[1] = (short)f2bf(lo.y);
            a[2] = (short)f2bf(lo.z); a[3] = (short)f2bf(lo.w);
            a[4] = (short)f2bf(hi.x); a[5] = (short)f2bf(hi.y);
            a[6] = (short)f2bf(hi.z); a[7] = (short)f2bf(hi.w);
        } else {
            a = *(const short8*)((const unsigned short*)Ax + (size_t)arow * 128 + c * 32 + k0);
        }
#pragma unroll
        for (int t = 0; t < 8; ++t) {
            short8 bfr = *(const short8*)&ws[(t * 16 + lr) * 136 + c * 32 + k0];
            acc[t] = __builtin_amdgcn_mfma_f32_16x16x32_bf16(a, bfr, acc[t], 0, 0, 0);
        }
    }

    // C/D layout (m89): col = lane&15, row = (lane>>4)*4 + reg
    if (MODE == 0) {
        unsigned short* out = (unsigned short*)outA;
#pragma unroll
        for (int t = 0; t < 8; ++t) {
            int col = t * 16 + lr;
#pragma unroll
            for (int r = 0; r < 4; ++r) {
                int row = brow + kg * 4 + r;
                if (row < n) out[(size_t)row * 128 + col] = f2bf(acc[t][r]);
            }
        }
    } else {
        float* oA = (float*)outA;
        float* oB = (float*)outB;
#pragma unroll
        for (int t = 0; t < 8; ++t) {
            int col = t * 16 + lr;
            float bv = (col < 64) ? biasA[col] : biasB[col - 64];
#pragma unroll
            for (int r = 0; r < 4; ++r) {
                int row = brow + kg * 4 + r;
                if (row < n) {
                    float v = acc[t][r] + bv;
                    if (col < 64) oA[(size_t)row * 64 + col] = v;
                    else          oB[(size_t)row * 64 + (col - 64)] = v;
                }
            }
        }
    }
}

// ---------------- fused CSR aggregation: half-wave pairing, 8-edge unroll ----------------
// out[v] = act( dv*( sum_e dis[s_e]*x[s_e] + dv*x[v] ) + bias ),  dv = dis[v]
// Lane covers 4 features (uint2 = 8B); lanes 0-31 take even edges, lanes 32-63
// odd edges; one load/addr chain serves two edges. shfl_xor(32) folds halves.

__global__ __launch_bounds__(256) void csr_agg_kernel(
        const unsigned short* __restrict__ hin, const int* __restrict__ row_beg,
        const int* __restrict__ row_end, const int* __restrict__ csr_src,
        const float* __restrict__ dis, const float* __restrict__ bias,
        unsigned short* __restrict__ out, int n, int relu) {
    int node = blockIdx.x * 4 + (threadIdx.x >> 6);
    if (node >= n) return;
    const int lane = threadIdx.x & 63;
    const int hi_half = lane >> 5;            // 0: even edges, 1: odd edges
    const unsigned foff = (lane & 31) * 8;    // byte offset of this lane's 4 features
    int beg = row_beg[node], end = row_end[node];
    float dv = dis[node];

    const char* hinb = (const char*)hin;

    float a0x = 0.f, a0y = 0.f, a0z = 0.f, a0w = 0.f;
    float a1x = 0.f, a1y = 0.f, a1z = 0.f, a1w = 0.f;
    float a2x = 0.f, a2y = 0.f, a2z = 0.f, a2w = 0.f;
    float a3x = 0.f, a3y = 0.f, a3z = 0.f, a3w = 0.f;

    int e = beg;
    // main: 4 pairs = 8 edges per iteration
    for (; e + 7 < end; e += 8) {
        int s0 = csr_src[e + 0 + hi_half];
        int s1 = csr_src[e + 2 + hi_half];
        int s2 = csr_src[e + 4 + hi_half];
        int s3 = csr_src[e + 6 + hi_half];
        float w0 = dis[s0], w1 = dis[s1], w2 = dis[s2], w3 = dis[s3];
        uint2 d0 = *(const uint2*)(hinb + (size_t)s0 * 256 + foff);
        uint2 d1 = *(const uint2*)(hinb + (size_t)s1 * 256 + foff);
        uint2 d2 = *(const uint2*)(hinb + (size_t)s2 * 256 + foff);
        uint2 d3 = *(const uint2*)(hinb + (size_t)s3 * 256 + foff);
        a0x += bf2f(d0.x & 0xffffu) * w0; a0y += bf2f(d0.x >> 16) * w0;
        a0z += bf2f(d0.y & 0xffffu) * w0; a0w += bf2f(d0.y >> 16) * w0;
        a1x += bf2f(d1.x & 0xffffu) * w1; a1y += bf2f(d1.x >> 16) * w1;
        a1z += bf2f(d1.y & 0xffffu) * w1; a1w += bf2f(d1.y >> 16) * w1;
        a2x += bf2f(d2.x & 0xffffu) * w2; a2y += bf2f(d2.x >> 16) * w2;
        a2z += bf2f(d2.y & 0xffffu) * w2; a2w += bf2f(d2.y >> 16) * w2;
        a3x += bf2f(d3.x & 0xffffu) * w3; a3y += bf2f(d3.x >> 16) * w3;
        a3z += bf2f(d3.y & 0xffffu) * w3; a3w += bf2f(d3.y >> 16) * w3;
    }
    // 1 pair = 2 edges
    for (; e + 1 < end; e += 2) {
        int s = csr_src[e + hi_half];
        float w = dis[s];
        uint2 d = *(const uint2*)(hinb + (size_t)s * 256 + foff);
        a0x += bf2f(d.x & 0xffffu) * w; a0y += bf2f(d.x >> 16) * w;
        a0z += bf2f(d.y & 0xffffu) * w; a0w += bf2f(d.y >> 16) * w;
    }
    // odd tail: both halves process it at half weight (sums to full via shfl fold)
    if (e < end) {
        int s = csr_src[e];
        float w = 0.5f * dis[s];
        uint2 d = *(const uint2*)(hinb + (size_t)s * 256 + foff);
        a1x += bf2f(d.x & 0xffffu) * w; a1y += bf2f(d.x >> 16) * w;
        a1z += bf2f(d.y & 0xffffu) * w; a1w += bf2f(d.y >> 16) * w;
    }

    float sx = (a0x + a1x) + (a2x + a3x);
    float sy = (a0y + a1y) + (a2y + a3y);
    float sz = (a0z + a1z) + (a2z + a3z);
    float sw = (a0w + a1w) + (a2w + a3w);
    // fold the two half-waves
    sx += __shfl_xor(sx, 32, 64);
    sy += __shfl_xor(sy, 32, 64);
    sz += __shfl_xor(sz, 32, 64);
    sw += __shfl_xor(sw, 32, 64);

    // self term + dv scale: out = dv*(sum + dv*self)
    uint2 sd = *(const uint2*)(hinb + (size_t)node * 256 + foff);
    sx = dv * (sx + dv * bf2f(sd.x & 0xffffu));
    sy = dv * (sy + dv * bf2f(sd.x >> 16));
    sz = dv * (sz + dv * bf2f(sd.y & 0xffffu));
    sw = dv * (sw + dv * bf2f(sd.y >> 16));

    if (bias) {
        float4 bb = *(const float4*)&bias[(lane & 31) * 4];
        sx += bb.x; sy += bb.y; sz += bb.z; sw += bb.w;
    }
    if (relu) {
        sx = fmaxf(sx, 0.f); sy = fmaxf(sy, 0.f);
        sz = fmaxf(sz, 0.f); sw = fmaxf(sw, 0.f);
    }
    if (lane < 32) {
        uint2 o;
        o.x = (unsigned)f2bf(sx) | ((unsigned)f2bf(sy) << 16);
        o.y = (unsigned)f2bf(sz) | ((unsigned)f2bf(sw) << 16);
        *(uint2*)((char*)out + (size_t)node * 256 + foff) = o;
    }
}

// ---------------- launcher ----------------

extern "C" void kernel_launch(void* const* d_in, const int* in_sizes, int n_in,
                              void* d_out, int out_size, void* d_ws, size_t ws_size,
                              hipStream_t stream) {
    const float* x   = (const float*)d_in[0];
    const void*  ei  = d_in[1];
    const float* W1  = (const float*)d_in[2];
    const float* b1  = (const float*)d_in[3];
    const float* Wmu = (const float*)d_in[4];
    const float* bmu = (const float*)d_in[5];
    const float* Wls = (const float*)d_in[6];
    const float* bls = (const float*)d_in[7];

    const int n = in_sizes[0] / 128;
    const int E = in_sizes[1] / 2;
    const int nb = (n + BNODES - 1) >> BSHIFT;      // 782 for n=100000 (<= NBMAX)
    const int epc = (E + CHUNKS - 1) / CHUNKS;      // edges per chunk

    float* out   = (float*)d_out;
    float* outMu = out;
    float* outLs = out + (size_t)n * 64;

    char* w = (char*)d_ws;
    auto alloc = [&](size_t bytes) { char* p = w; w += align_up(bytes, 256); return p; };
    int*            hmat    = (int*)           alloc((size_t)CHUNKS * nb * 4);
    int*            btot    = (int*)           alloc(NBMAX * 4);
    int*            bbase   = (int*)           alloc(NBMAX * 4);
    unsigned*       binned  = (unsigned*)      alloc((size_t)E * 4);
    int*            row_beg = (int*)           alloc((size_t)n * 4);
    int*            row_end = (int*)           alloc((size_t)n * 4);
    float*          dis     = (float*)         alloc((size_t)n * 4);
    int*            csr_src = (int*)           alloc((size_t)E * 4);
    unsigned short* Wt1     = (unsigned short*)alloc(128 * 128 * 2);
    unsigned short* Wtcat   = (unsigned short*)alloc(128 * 128 * 2);
    unsigned short* xW      = (unsigned short*)alloc((size_t)n * 128 * 2);
    unsigned short* h       = (unsigned short*)alloc((size_t)n * 128 * 2);
    unsigned short* hagg    = (unsigned short*)alloc((size_t)n * 128 * 2);

    // ---- graph preprocessing: deterministic chunked counting sort ----
    chunk_hist_kernel<<<CHUNKS, 256, 0, stream>>>(ei, hmat, E, n, nb, epc);
    bucket_scan_cols_kernel<<<nb, 256, 0, stream>>>(hmat, btot, nb);
    base_scan_kernel<<<1, NBMAX, 0, stream>>>(btot, bbase, nb);
    chunk_scatter_kernel<<<CHUNKS, 256, 0, stream>>>(ei, hmat, bbase, binned, E, n, nb, epc);
    bucket_csr_kernel<<<nb, 256, 0, stream>>>(binned, bbase, btot, dis, row_beg, row_end,
                                              csr_src, n);
    prep_weights_kernel<<<128, 256, 0, stream>>>(W1, Wmu, Wls, Wt1, Wtcat);

    const int gblocks = (n + 63) / 64;

    // ---- layer 1: h = relu(A(x@W1) + b1) ----
    mfma_gemm_kernel<0><<<gblocks, 256, 0, stream>>>(x, Wt1, nullptr, nullptr, xW, nullptr, n);
    csr_agg_kernel<<<(n + 3) / 4, 256, 0, stream>>>(xW, row_beg, row_end, csr_src,
                                                    dis, b1, h, n, 1);

    // ---- layer 2+3: hagg = A h; [mu|ls] = hagg @ [Wmu|Wls] + [bmu|bls] ----
    csr_agg_kernel<<<(n + 3) / 4, 256, 0, stream>>>(h, row_beg, row_end, csr_src,
                                                    dis, nullptr, hagg, n, 0);
    mfma_gemm_kernel<1><<<gblocks, 256, 0, stream>>>(hagg, Wtcat, bmu, bls, outMu, outLs, n);
}